// Round 18
// baseline (102.073 us; speedup 1.0000x reference)
//
#include <hip/hip_runtime.h>

#define SCALE 0.044194173824159216f   // 1/sqrt(512)

typedef _Float16 half8 __attribute__((ext_vector_type(8)));
typedef _Float16 half4 __attribute__((ext_vector_type(4)));
typedef float    f32x4 __attribute__((ext_vector_type(4)));

#define MFMA(A, B, Cc) __builtin_amdgcn_mfma_f32_16x16x32_f16((A), (B), (Cc), 0, 0, 0)

// ---------------- ws layout (bytes) ----------------
#define X16_OFF 0ull
#define Y16_OFF 33554432ull     // y = x * G   [32768,512] fp16
#define MT_OFF  67108864ull     // G^T-layout Mt[g][e], 512x512 fp16 (512KB)
#define MP_OFF  68157440ull     // split-K partials [8][512][512] fp32 (8MB)
#define VT_OFF  100663296ull
#define W16_OFF 134217728ull    // W_all fp16 [1536][512]: Wq~(scaled), Wk, Wv
#define WS_NEED 135790592ull

typedef __attribute__((address_space(1))) const unsigned int glb_t;
typedef __attribute__((address_space(3))) unsigned int lds_t;

// async global->LDS, 16B per lane; LDS dest = wave-uniform base + lane*16
__device__ __forceinline__ void gl16(const void* g, void* l) {
  __builtin_amdgcn_global_load_lds((glb_t*)g, (lds_t*)l, 16, 0, 0);
}

// swizzled read of a [R][64] fp16 tile (row stride 128B): LDS[row][u16] = glob[row][u16^(row&7)]
__device__ __forceinline__ half8 ldf64(const _Float16* buf, int row, int colh) {
  int byte = row * 128 + (((colh) << 1) ^ ((row & 7) << 4));
  return *(const half8*)((const char*)buf + byte);
}
// swizzled read of a [R][128] fp16 tile (row stride 256B)
__device__ __forceinline__ half8 ldf128(const _Float16* buf, int row, int colh) {
  int byte = row * 256 + (((colh) << 1) ^ ((row & 7) << 4));
  return *(const half8*)((const char*)buf + byte);
}

// ================= KmmA v3: split-K partials, 4g x 4e register blocking =================
// part[fc][g][e] = sum_{f in chunk fc} Wk[f][g]*Wq[f][e].
__global__ __launch_bounds__(256)
void kmmA(const float* __restrict__ Wq, const float* __restrict__ Wk,
          float* __restrict__ part)
{
  const int blk = blockIdx.x, t = threadIdx.x;
  const int fc = blk & 7, ot = blk >> 3;           // 64 output tiles
  const int G0 = (ot >> 3) * 64, E0 = (ot & 7) * 64;
  const int gb = G0 + (t & 15) * 4;
  const int eb = E0 + (t >> 4) * 4;
  float acc[4][4] = {};
  const int f0 = fc * 64;
  #pragma unroll 4
  for (int f = f0; f < f0 + 64; ++f) {
    f32x4 kv = *(const f32x4*)(Wk + (size_t)f * 512 + gb);
    f32x4 qv = *(const f32x4*)(Wq + (size_t)f * 512 + eb);
    #pragma unroll
    for (int i = 0; i < 4; ++i)
      #pragma unroll
      for (int j = 0; j < 4; ++j)
        acc[i][j] += kv[i] * qv[j];
  }
  float* pp = part + (size_t)fc * 262144;
  #pragma unroll
  for (int i = 0; i < 4; ++i)
    *(f32x4*)(pp + (size_t)(gb + i) * 512 + eb) =
        (f32x4){acc[i][0], acc[i][1], acc[i][2], acc[i][3]};
}

// ================= K0c: fused {kmmB (blocks 0..1023)} + {fp32->fp16 convert (rest)} =================
// kmmB's latency-bound blocks hide under the BW-bound cvt (removes serial kmmB + 1 launch gap).
__global__ __launch_bounds__(256)
void k0c(const float* __restrict__ x, const float* __restrict__ Wq,
         const float* __restrict__ Wk, const float* __restrict__ Wv,
         _Float16* __restrict__ x16, _Float16* __restrict__ w16,
         const float* __restrict__ part, _Float16* __restrict__ Mt)
{
  if (blockIdx.x < 1024) {
    // ---- kmmB: Mt[g][e] = fp16(SCALE * sum_fc part[fc][g][e]) ----
    const int idx = blockIdx.x * 256 + threadIdx.x;   // -> 262144
    float s = 0.f;
    #pragma unroll
    for (int fc = 0; fc < 8; ++fc)
      s += part[(size_t)fc * 262144 + idx];
    Mt[idx] = (_Float16)(s * SCALE);
  } else {
    // ---- cvt: x fp32->fp16; W fp32->fp16 with SCALE folded into Wq ----
    const long long NX = 16777216LL;   // 4*8192*512
    long long base = ((long long)(blockIdx.x - 1024) * 256 + threadIdx.x) * 8;
    const float* src;
    _Float16* dst;
    float sc = 1.0f;
    if (base < NX) {
      src = x + base; dst = x16 + base;
    } else {
      long long o = base - NX;             // 0 .. 786431
      int ws = (int)(o >> 18);
      long long oo = o & 262143LL;
      src = (ws == 0 ? Wq : (ws == 1 ? Wk : Wv)) + oo;
      dst = w16 + o;
      if (ws == 0) sc = SCALE;
    }
    const float4* p = (const float4*)src;
    float4 f0 = p[0], f1 = p[1];
    half8 v;
    v[0] = (_Float16)(f0.x * sc); v[1] = (_Float16)(f0.y * sc);
    v[2] = (_Float16)(f0.z * sc); v[3] = (_Float16)(f0.w * sc);
    v[4] = (_Float16)(f1.x * sc); v[5] = (_Float16)(f1.y * sc);
    v[6] = (_Float16)(f1.z * sc); v[7] = (_Float16)(f1.w * sc);
    *(half8*)dst = v;
  }
}

// ================= K1: 128x128 GEMM, fp16 staged, double-buffered, counted vmcnt =================
// ntile 0..3: y = x16 @ Mt^T (row-major out) ; ntile 4..7: vT = (x16 @ Wv^T)^T
__global__ __launch_bounds__(256)
void k1_gemm(const _Float16* __restrict__ x16, const _Float16* __restrict__ w16,
             const _Float16* __restrict__ Mt, _Float16* __restrict__ y16,
             _Float16* __restrict__ vT)
{
  __shared__ _Float16 xs[2][8192];   // 2x16KB, [128 s][64 e], src-swizzled
  __shared__ _Float16 wl[2][8192];   // 2x16KB, [128 n][64 e], src-swizzled

  // bijective XCD swizzle: 2048 blocks = 8 XCDs x 256
  const int id  = blockIdx.x;
  const int swz = (id & 7) * 256 + (id >> 3);
  const int ntile = swz & 7;
  const int stile = swz >> 3;
  const bool vpath = (ntile >= 4);
  const int tid = threadIdx.x, lane = tid & 63, w = tid >> 6;
  const int l15 = lane & 15, h = lane >> 4;
  const int wm = w >> 1, wn = w & 1;

  const _Float16* xb = x16 + (size_t)stile * 128 * 512;
  const _Float16* wb = vpath ? w16 + (size_t)(1024 + (ntile & 3) * 128) * 512
                             : Mt  + (size_t)((ntile & 3) * 128) * 512;

  int rowi[4], coli[4];
  #pragma unroll
  for (int i = 0; i < 4; ++i) {
    int unit = i * 256 + w * 64 + lane;
    int row = unit >> 3, u = unit & 7;
    rowi[i] = row;
    coli[i] = (u ^ (row & 7)) << 3;
  }

  f32x4 acc[4][4] = {};

  #pragma unroll
  for (int i = 0; i < 4; ++i) {
    int ub = i * 256 + w * 64;
    gl16(xb + (size_t)rowi[i] * 512 + coli[i], &xs[0][ub * 8]);
    gl16(wb + (size_t)rowi[i] * 512 + coli[i], &wl[0][ub * 8]);
  }

  for (int kk = 0; kk < 8; ++kk) {
    const int cur = kk & 1;
    if (kk < 7) {
      const int nxt = cur ^ 1;
      #pragma unroll
      for (int i = 0; i < 4; ++i) {
        int ub = i * 256 + w * 64;
        gl16(xb + (size_t)rowi[i] * 512 + (kk + 1) * 64 + coli[i], &xs[nxt][ub * 8]);
        gl16(wb + (size_t)rowi[i] * 512 + (kk + 1) * 64 + coli[i], &wl[nxt][ub * 8]);
      }
      asm volatile("s_waitcnt vmcnt(8)" ::: "memory");
    } else {
      asm volatile("s_waitcnt vmcnt(0)" ::: "memory");
    }
    __builtin_amdgcn_s_barrier();
    __builtin_amdgcn_sched_barrier(0);

    #pragma unroll
    for (int ks = 0; ks < 2; ++ks) {
      half8 a[4], bf[4];
      if (!vpath) {
        #pragma unroll
        for (int mr = 0; mr < 4; ++mr) a[mr]  = ldf64(xs[cur], wm * 64 + mr * 16 + l15, ks * 32 + h * 8);
        #pragma unroll
        for (int nr = 0; nr < 4; ++nr) bf[nr] = ldf64(wl[cur], wn * 64 + nr * 16 + l15, ks * 32 + h * 8);
      } else {
        #pragma unroll
        for (int mr = 0; mr < 4; ++mr) a[mr]  = ldf64(wl[cur], wm * 64 + mr * 16 + l15, ks * 32 + h * 8);
        #pragma unroll
        for (int nr = 0; nr < 4; ++nr) bf[nr] = ldf64(xs[cur], wn * 64 + nr * 16 + l15, ks * 32 + h * 8);
      }
      #pragma unroll
      for (int mr = 0; mr < 4; ++mr)
        #pragma unroll
        for (int nr = 0; nr < 4; ++nr)
          acc[mr][nr] = MFMA(a[mr], bf[nr], acc[mr][nr]);
    }

    __builtin_amdgcn_sched_barrier(0);
    __builtin_amdgcn_s_barrier();
  }

  if (!vpath) {
    const int m0 = stile * 128 + wm * 64;
    const int n0 = (ntile & 3) * 128 + wn * 64;
    #pragma unroll
    for (int mr = 0; mr < 4; ++mr)
      #pragma unroll
      for (int nr = 0; nr < 4; ++nr)
        #pragma unroll
        for (int r = 0; r < 4; ++r)
          y16[(size_t)(m0 + mr * 16 + h * 4 + r) * 512 + n0 + nr * 16 + l15] =
              (_Float16)acc[mr][nr][r];
  } else {
    const int d0 = (ntile & 3) * 128 + wm * 64;
    const int sg = stile * 128 + wn * 64;
    const int bb = sg >> 13, s0 = sg & 8191;
    _Float16* dst = vT + (size_t)bb * 512 * 8192;
    #pragma unroll
    for (int mr = 0; mr < 4; ++mr)
      #pragma unroll
      for (int nr = 0; nr < 4; ++nr)
        #pragma unroll
        for (int r = 0; r < 4; ++r)
          dst[(size_t)(d0 + mr * 16 + h * 4 + r) * 8192 + s0 + nr * 16 + l15] =
              (_Float16)acc[mr][nr][r];
  }
}

// ================= K2: chunked attention; S = y . x16^T ; PV from vT =================
// counted-vmcnt pipeline: stage next -> vmcnt(4) -> barrier -> compute -> barrier.
// PV prologue stage hoisted above softmax (hides L2/L3 latency under VALU).
__global__ __launch_bounds__(256)
void k2_attn(const _Float16* __restrict__ y16, const _Float16* __restrict__ x16,
             const _Float16* __restrict__ vT, float* __restrict__ out)
{
  __shared__ _Float16 kj[2][128 * 64];   // 2x16KB: S: [128 j][64 e] ; PV: [64 d][128 j]
  __shared__ _Float16 p_lds[64 * 128];   // 16KB, [64 q][128 j], swizzled, wave-local use

  const int id = blockIdx.x;             // 512 blocks = 8 XCDs x 64; contiguous c per XCD
  const int sz = (id & 7) * 64 + (id >> 3);
  const int b = sz >> 7, c = sz & 127;
  const int tid = threadIdx.x, lane = tid & 63, w = tid >> 6;
  const int l15 = lane & 15, h = lane >> 4;
  const int jbase = c * 64 - 64;

  const _Float16* qrow = y16 + (size_t)(b * 8192 + c * 64 + w * 16 + l15) * 512;
  half8 qa[16];
  #pragma unroll
  for (int ks = 0; ks < 16; ++ks) qa[ks] = *(const half8*)(qrow + ks * 32 + h * 8);

  const _Float16* kb = x16 + (size_t)b * 8192 * 512;
  const _Float16* vb = vT + (size_t)b * 512 * 8192;

  int srow[4], scol[4];
  #pragma unroll
  for (int i = 0; i < 4; ++i) {
    int unit = i * 256 + w * 64 + lane;
    int row = unit >> 3, u = unit & 7;
    int sj = jbase + row; if (sj < 0) sj = 0;   // c==0: masked below
    srow[i] = sj;
    scol[i] = (u ^ (row & 7)) << 3;
  }
  int prow[4], pjs[4];
  #pragma unroll
  for (int i = 0; i < 4; ++i) {
    int unit = i * 256 + w * 64 + lane;
    int row = unit >> 4, u = unit & 15;
    int u2 = (u & 8) | ((u & 7) ^ (row & 7));
    int js = jbase + u2 * 8; if (js < 0) js = 0; // c==0: p==0 exactly there
    prow[i] = row;
    pjs[i] = js;
  }

  // ---- S phase: counted-vmcnt pipeline ----
  f32x4 S[8] = {};
  #pragma unroll
  for (int i = 0; i < 4; ++i)
    gl16(kb + (size_t)srow[i] * 512 + scol[i], &kj[0][(i * 256 + w * 64) * 8]);

  #pragma unroll
  for (int ee = 0; ee < 8; ++ee) {
    if (ee < 7) {
      #pragma unroll
      for (int i = 0; i < 4; ++i)
        gl16(kb + (size_t)srow[i] * 512 + (ee + 1) * 64 + scol[i],
             &kj[(ee + 1) & 1][(i * 256 + w * 64) * 8]);
      asm volatile("s_waitcnt vmcnt(4)" ::: "memory");
    } else {
      asm volatile("s_waitcnt vmcnt(0)" ::: "memory");
    }
    __builtin_amdgcn_s_barrier();
    __builtin_amdgcn_sched_barrier(0);

    #pragma unroll
    for (int ks = 0; ks < 2; ++ks) {
      #pragma unroll
      for (int nt = 0; nt < 8; ++nt) {
        half8 bf = ldf64(kj[ee & 1], nt * 16 + l15, ks * 32 + h * 8);
        S[nt] = MFMA(qa[ee * 2 + ks], bf, S[nt]);
      }
    }
    __builtin_amdgcn_sched_barrier(0);
    __builtin_amdgcn_s_barrier();
  }

  // ---- PV prologue stage (hoisted above softmax) ----
  #pragma unroll
  for (int i = 0; i < 4; ++i)
    gl16(vb + (size_t)prow[i] * 8192 + pjs[i], &kj[0][(i * 256 + w * 64) * 8]);

  // ---- masked softmax (VALU; overlaps PV prologue loads) ----
  #pragma unroll
  for (int jt = 0; jt < 8; ++jt) {
    int j = jt * 16 + l15;
    #pragma unroll
    for (int r = 0; r < 4; ++r) {
      int ql = w * 16 + h * 4 + r;
      bool valid = (j < 64 + ql) && ((c > 0) || (j >= 64));
      S[jt][r] = valid ? S[jt][r] : -1e30f;
    }
  }
  #pragma unroll
  for (int r = 0; r < 4; ++r) {
    float mx = -1e30f;
    #pragma unroll
    for (int jt = 0; jt < 8; ++jt) mx = fmaxf(mx, S[jt][r]);
    mx = fmaxf(mx, __shfl_xor(mx, 1));
    mx = fmaxf(mx, __shfl_xor(mx, 2));
    mx = fmaxf(mx, __shfl_xor(mx, 4));
    mx = fmaxf(mx, __shfl_xor(mx, 8));
    float sum = 0.f;
    #pragma unroll
    for (int jt = 0; jt < 8; ++jt) {
      float sv = S[jt][r];
      float pe = (sv > -1e29f) ? __expf(sv - mx) : 0.f;
      S[jt][r] = pe;
      sum += pe;
    }
    sum += __shfl_xor(sum, 1);
    sum += __shfl_xor(sum, 2);
    sum += __shfl_xor(sum, 4);
    sum += __shfl_xor(sum, 8);
    float inv = (sum > 0.f) ? (1.0f / sum) : 0.f;   // fully-masked row -> p = 0
    #pragma unroll
    for (int jt = 0; jt < 8; ++jt) {
      int row = w * 16 + h * 4 + r, col = jt * 16 + l15;
      _Float16 ph = (_Float16)(S[jt][r] * inv);
      *(_Float16*)((char*)p_lds + row * 256 + ((col << 1) ^ ((row & 7) << 4))) = ph;
    }
  }
  half8 pa[4];
  #pragma unroll
  for (int ks = 0; ks < 4; ++ks) {
    int row = w * 16 + l15, colh = ks * 32 + h * 8;
    pa[ks] = *(const half8*)((const char*)p_lds + row * 256 + ((colh << 1) ^ ((row & 7) << 4)));
  }

  // ---- PV phase: counted-vmcnt pipeline ----
  float* ob = out + (size_t)(b * 8192 + c * 64 + w * 16) * 512;
  #pragma unroll
  for (int dd = 0; dd < 8; ++dd) {
    if (dd < 7) {
      #pragma unroll
      for (int i = 0; i < 4; ++i)
        gl16(vb + (size_t)((dd + 1) * 64 + prow[i]) * 8192 + pjs[i],
             &kj[(dd + 1) & 1][(i * 256 + w * 64) * 8]);
      asm volatile("s_waitcnt vmcnt(4)" ::: "memory");   // over-waits retired stores: safe
    } else {
      asm volatile("s_waitcnt vmcnt(0)" ::: "memory");
    }
    __builtin_amdgcn_s_barrier();
    __builtin_amdgcn_sched_barrier(0);

    f32x4 o[4] = {};
    #pragma unroll
    for (int ks = 0; ks < 4; ++ks) {
      #pragma unroll
      for (int nr = 0; nr < 4; ++nr) {
        half8 bf = ldf128(kj[dd & 1], nr * 16 + l15, ks * 32 + h * 8);
        o[nr] = MFMA(pa[ks], bf, o[nr]);
      }
    }
    #pragma unroll
    for (int nr = 0; nr < 4; ++nr)
      #pragma unroll
      for (int r = 0; r < 4; ++r)
        ob[(size_t)(h * 4 + r) * 512 + dd * 64 + nr * 16 + l15] = o[nr][r];
    __builtin_amdgcn_sched_barrier(0);
    __builtin_amdgcn_s_barrier();
  }
}

// ================= fallback: round-1 fused kernel (used only if ws too small) =================
__device__ __forceinline__ int swzb(int row, int colByte) {
  return colByte ^ ((row & 7) << 4);
}
__device__ __forceinline__ half8 ldw_frag(const float* __restrict__ W, int row, int e0) {
  const float4* p = reinterpret_cast<const float4*>(W + ((size_t)row << 9) + e0);
  float4 f0 = p[0];
  float4 f1 = p[1];
  half8 v;
  v[0] = (_Float16)f0.x; v[1] = (_Float16)f0.y; v[2] = (_Float16)f0.z; v[3] = (_Float16)f0.w;
  v[4] = (_Float16)f1.x; v[5] = (_Float16)f1.y; v[6] = (_Float16)f1.z; v[7] = (_Float16)f1.w;
  return v;
}
__device__ __forceinline__ half8 ldl_frag(const unsigned short* buf, int row, int col, int strideBytes) {
  int byte = row * strideBytes + swzb(row, col << 1);
  return *reinterpret_cast<const half8*>(reinterpret_cast<const char*>(buf) + byte);
}

__global__ __launch_bounds__(256, 1)
void ep_fused(const float* __restrict__ x, const float* __restrict__ Wq,
              const float* __restrict__ Wk, const float* __restrict__ Wv,
              float* __restrict__ out)
{
  __shared__ unsigned short xs[128 * 512];
  __shared__ unsigned short kv[64 * 128];
  __shared__ unsigned short pq[64 * 128];

  const int bc   = blockIdx.x;
  const int b    = bc >> 7;
  const int c    = bc & 127;
  const int tid  = threadIdx.x;
  const int lane = tid & 63;
  const int w    = tid >> 6;
  const int l15  = lane & 15;
  const int h    = lane >> 4;

  const float* xb = x + (size_t)b * (8192 * 512);
  #pragma unroll
  for (int i = 0; i < 32; ++i) {
    int unit = tid + (i << 8);
    int row  = unit >> 6;
    int e0   = (unit & 63) << 3;
    half8 v;
    if (c == 0 && row < 64) {
      #pragma unroll
      for (int t = 0; t < 8; ++t) v[t] = (_Float16)0.0f;
    } else {
      int s = c * 64 - 64 + row;
      const float4* p = reinterpret_cast<const float4*>(xb + (size_t)s * 512 + e0);
      float4 f0 = p[0], f1 = p[1];
      v[0] = (_Float16)f0.x; v[1] = (_Float16)f0.y; v[2] = (_Float16)f0.z; v[3] = (_Float16)f0.w;
      v[4] = (_Float16)f1.x; v[5] = (_Float16)f1.y; v[6] = (_Float16)f1.z; v[7] = (_Float16)f1.w;
    }
    int byte = (row << 10) + swzb(row, e0 << 1);
    *reinterpret_cast<half8*>(reinterpret_cast<char*>(xs) + byte) = v;
  }
  __syncthreads();

  f32x4 Sacc[8] = {};
  const int d0 = (w << 4) + (h << 2);

  for (int dt = 0; dt < 8; ++dt) {
    const int drow = (dt << 6) + (w << 4) + l15;

    f32x4 qa[4] = {};
    for (int ks = 0; ks < 16; ++ks) {
      half8 a = ldw_frag(Wq, drow, (ks << 5) + (h << 3));
      #pragma unroll
      for (int nt = 0; nt < 4; ++nt) {
        half8 bf = ldl_frag(xs, 64 + (nt << 4) + l15, (ks << 5) + (h << 3), 1024);
        qa[nt] = MFMA(a, bf, qa[nt]);
      }
    }
    #pragma unroll
    for (int nt = 0; nt < 4; ++nt) {
      int q = (nt << 4) + l15;
      half4 hv;
      hv[0] = (_Float16)qa[nt][0]; hv[1] = (_Float16)qa[nt][1];
      hv[2] = (_Float16)qa[nt][2]; hv[3] = (_Float16)qa[nt][3];
      *reinterpret_cast<half4*>(reinterpret_cast<char*>(pq) + q * 128 + swzb(q, d0 << 1)) = hv;
    }

    f32x4 ka[8] = {};
    for (int ks = 0; ks < 16; ++ks) {
      half8 a = ldw_frag(Wk, drow, (ks << 5) + (h << 3));
      #pragma unroll
      for (int nt = 0; nt < 8; ++nt) {
        half8 bf = ldl_frag(xs, (nt << 4) + l15, (ks << 5) + (h << 3), 1024);
        ka[nt] = MFMA(a, bf, ka[nt]);
      }
    }
    #pragma unroll
    for (int nt = 0; nt < 8; ++nt) {
      int j = (nt << 4) + l15;
      half4 hv;
      hv[0] = (_Float16)ka[nt][0]; hv[1] = (_Float16)ka[nt][1];
      hv[2] = (_Float16)ka[nt][2]; hv[3] = (_Float16)ka[nt][3];
      *reinterpret_cast<half4*>(reinterpret_cast<char*>(kv) + j * 128 + swzb(j, d0 << 1)) = hv;
    }
    __syncthreads();

    #pragma unroll
    for (int ksd = 0; ksd < 2; ++ksd) {
      half8 a = ldl_frag(pq, (w << 4) + l15, (ksd << 5) + (h << 3), 128);
      #pragma unroll
      for (int nt = 0; nt < 8; ++nt) {
        half8 bf = ldl_frag(kv, (nt << 4) + l15, (ksd << 5) + (h << 3), 128);
        Sacc[nt] = MFMA(a, bf, Sacc[nt]);
      }
    }
    __syncthreads();
  }

  const float scale = SCALE;
  #pragma unroll
  for (int nt = 0; nt < 8; ++nt) {
    int j = (nt << 4) + l15;
    #pragma unroll
    for (int r = 0; r < 4; ++r) {
      int qrow = (w << 4) + (h << 2) + r;
      bool valid = (j < 64 + qrow) && ((c > 0) || (j >= 64));
      Sacc[nt][r] = valid ? Sacc[nt][r] * scale : -1e30f;
    }
  }
  float inv[4];
  #pragma unroll
  for (int r = 0; r < 4; ++r) {
    float mx = -1e30f;
    #pragma unroll
    for (int nt = 0; nt < 8; ++nt) mx = fmaxf(mx, Sacc[nt][r]);
    mx = fmaxf(mx, __shfl_xor(mx, 1));
    mx = fmaxf(mx, __shfl_xor(mx, 2));
    mx = fmaxf(mx, __shfl_xor(mx, 4));
    mx = fmaxf(mx, __shfl_xor(mx, 8));
    float sum = 0.f;
    #pragma unroll
    for (int nt = 0; nt < 8; ++nt) {
      float sv = Sacc[nt][r];
      float pe = (sv > -1e29f) ? __expf(sv - mx) : 0.f;
      Sacc[nt][r] = pe;
      sum += pe;
    }
    sum += __shfl_xor(sum, 1);
    sum += __shfl_xor(sum, 2);
    sum += __shfl_xor(sum, 4);
    sum += __shfl_xor(sum, 8);
    inv[r] = (sum > 0.f) ? (1.0f / sum) : 0.f;
  }
  #pragma unroll
  for (int nt = 0; nt < 8; ++nt) {
    int j = (nt << 4) + l15;
    #pragma unroll
    for (int r = 0; r < 4; ++r) {
      int qrow = (w << 4) + (h << 2) + r;
      _Float16 ph = (_Float16)(Sacc[nt][r] * inv[r]);
      *reinterpret_cast<_Float16*>(reinterpret_cast<char*>(pq) + qrow * 256 + swzb(qrow, j << 1)) = ph;
    }
  }
  __syncthreads();

  for (int dt = 0; dt < 8; ++dt) {
    const int dcol = (dt << 6) + (w << 4) + l15;

    f32x4 va[8] = {};
    for (int ks = 0; ks < 16; ++ks) {
      half8 bf = ldw_frag(Wv, dcol, (ks << 5) + (h << 3));
      #pragma unroll
      for (int mt = 0; mt < 8; ++mt) {
        half8 a = ldl_frag(xs, (mt << 4) + l15, (ks << 5) + (h << 3), 1024);
        va[mt] = MFMA(a, bf, va[mt]);
      }
    }
    {
      int dl = (w << 4) + l15;
      #pragma unroll
      for (int mt = 0; mt < 8; ++mt) {
        int j0 = (mt << 4) + (h << 2);
        half4 hv;
        hv[0] = (_Float16)va[mt][0]; hv[1] = (_Float16)va[mt][1];
        hv[2] = (_Float16)va[mt][2]; hv[3] = (_Float16)va[mt][3];
        *reinterpret_cast<half4*>(reinterpret_cast<char*>(kv) + dl * 256 + swzb(dl, j0 << 1)) = hv;
      }
    }
    __syncthreads();

    f32x4 oa[4] = {};
    #pragma unroll
    for (int ks = 0; ks < 4; ++ks) {
      half8 a = ldl_frag(pq, (w << 4) + l15, (ks << 5) + (h << 3), 256);
      #pragma unroll
      for (int nt = 0; nt < 4; ++nt) {
        half8 bf = ldl_frag(kv, (nt << 4) + l15, (ks << 5) + (h << 3), 256);
        oa[nt] = MFMA(a, bf, oa[nt]);
      }
    }
    #pragma unroll
    for (int nt = 0; nt < 4; ++nt) {
      int d = (dt << 6) + (nt << 4) + l15;
      #pragma unroll
      for (int r = 0; r < 4; ++r) {
        int qrow = (w << 4) + (h << 2) + r;
        out[((size_t)(b * 8192 + (c << 6) + qrow) << 9) + d] = oa[nt][r];
      }
    }
    __syncthreads();
  }
}

extern "C" void kernel_launch(void* const* d_in, const int* in_sizes, int n_in,
                              void* d_out, int out_size, void* d_ws, size_t ws_size,
                              hipStream_t stream) {
  const float* x  = (const float*)d_in[0];
  const float* Wq = (const float*)d_in[1];
  const float* Wk = (const float*)d_in[2];
  const float* Wv = (const float*)d_in[3];
  float* out = (float*)d_out;
  (void)in_sizes; (void)n_in; (void)out_size;

  if (d_ws != nullptr && ws_size >= WS_NEED) {
    char* ws = (char*)d_ws;
    _Float16* x16 = (_Float16*)(ws + X16_OFF);
    _Float16* y16 = (_Float16*)(ws + Y16_OFF);
    _Float16* Mt  = (_Float16*)(ws + MT_OFF);
    float*    Mp  = (float*)(ws + MP_OFF);
    _Float16* vT  = (_Float16*)(ws + VT_OFF);
    _Float16* w16 = (_Float16*)(ws + W16_OFF);

    hipLaunchKernelGGL(kmmA, dim3(512), dim3(256), 0, stream, Wq, Wk, Mp);
    hipLaunchKernelGGL(k0c, dim3(9600), dim3(256), 0, stream, x, Wq, Wk, Wv, x16, w16, Mp, Mt);
    hipLaunchKernelGGL(k1_gemm, dim3(2048), dim3(256), 0, stream, x16, w16, Mt, y16, vT);
    hipLaunchKernelGGL(k2_attn, dim3(512), dim3(256), 0, stream, y16, x16, vT, out);
  } else {
    hipLaunchKernelGGL(ep_fused, dim3(512), dim3(256), 0, stream, x, Wq, Wk, Wv, out);
  }
}

// Round 19
// 97.084 us; speedup vs baseline: 1.0514x; 1.0514x over previous
//
#include <hip/hip_runtime.h>

#define SCALE 0.044194173824159216f   // 1/sqrt(512)

typedef _Float16 half8 __attribute__((ext_vector_type(8)));
typedef _Float16 half4 __attribute__((ext_vector_type(4)));
typedef float    f32x4 __attribute__((ext_vector_type(4)));

#define MFMA(A, B, Cc) __builtin_amdgcn_mfma_f32_16x16x32_f16((A), (B), (Cc), 0, 0, 0)

// ---------------- ws layout (bytes) ----------------
#define X16_OFF 0ull
#define Y16_OFF 33554432ull     // y = x * G   [32768,512] fp16
#define MT_OFF  67108864ull     // G^T-layout Mt[g][e], 512x512 fp16 (512KB)
#define MP_OFF  68157440ull     // split-K partials [8][512][512] fp32 (8MB)
#define VT_OFF  100663296ull
#define W16_OFF 134217728ull    // W_all fp16 [1536][512]: Wq~(scaled), Wk, Wv
#define WS_NEED 135790592ull

typedef __attribute__((address_space(1))) const unsigned int glb_t;
typedef __attribute__((address_space(3))) unsigned int lds_t;

// async global->LDS, 16B per lane; LDS dest = wave-uniform base + lane*16
__device__ __forceinline__ void gl16(const void* g, void* l) {
  __builtin_amdgcn_global_load_lds((glb_t*)g, (lds_t*)l, 16, 0, 0);
}

// swizzled read of a [R][64] fp16 tile (row stride 128B): LDS[row][u16] = glob[row][u16^(row&7)]
__device__ __forceinline__ half8 ldf64(const _Float16* buf, int row, int colh) {
  int byte = row * 128 + (((colh) << 1) ^ ((row & 7) << 4));
  return *(const half8*)((const char*)buf + byte);
}
// swizzled read of a [R][128] fp16 tile (row stride 256B)
__device__ __forceinline__ half8 ldf128(const _Float16* buf, int row, int colh) {
  int byte = row * 256 + (((colh) << 1) ^ ((row & 7) << 4));
  return *(const half8*)((const char*)buf + byte);
}

// ================= K0m: fused {kmmA v3 (blocks 0..511)} + {fp32->fp16 convert (rest)} =================
// kmmA's latency-bound blocks dispatch first and finish under the BW-bound cvt.
__global__ __launch_bounds__(256)
void k0m(const float* __restrict__ x, const float* __restrict__ Wq,
         const float* __restrict__ Wk, const float* __restrict__ Wv,
         _Float16* __restrict__ x16, _Float16* __restrict__ w16,
         float* __restrict__ part)
{
  if (blockIdx.x < 512) {
    // ---- kmmA v3: part[fc][g][e] = sum_{f in chunk fc} Wk[f][g]*Wq[f][e]; 4g x 4e blocking ----
    const int blk = blockIdx.x, t = threadIdx.x;
    const int fc = blk & 7, ot = blk >> 3;           // 64 output tiles
    const int G0 = (ot >> 3) * 64, E0 = (ot & 7) * 64;
    const int gb = G0 + (t & 15) * 4;
    const int eb = E0 + (t >> 4) * 4;
    float acc[4][4] = {};
    const int f0 = fc * 64;
    #pragma unroll 4
    for (int f = f0; f < f0 + 64; ++f) {
      f32x4 kv = *(const f32x4*)(Wk + (size_t)f * 512 + gb);
      f32x4 qv = *(const f32x4*)(Wq + (size_t)f * 512 + eb);
      #pragma unroll
      for (int i = 0; i < 4; ++i)
        #pragma unroll
        for (int j = 0; j < 4; ++j)
          acc[i][j] += kv[i] * qv[j];
    }
    float* pp = part + (size_t)fc * 262144;
    #pragma unroll
    for (int i = 0; i < 4; ++i)
      *(f32x4*)(pp + (size_t)(gb + i) * 512 + eb) =
          (f32x4){acc[i][0], acc[i][1], acc[i][2], acc[i][3]};
  } else {
    // ---- cvt: x fp32->fp16; W fp32->fp16 with SCALE folded into Wq ----
    const long long NX = 16777216LL;   // 4*8192*512
    long long base = ((long long)(blockIdx.x - 512) * 256 + threadIdx.x) * 8;
    const float* src;
    _Float16* dst;
    float sc = 1.0f;
    if (base < NX) {
      src = x + base; dst = x16 + base;
    } else {
      long long o = base - NX;             // 0 .. 786431
      int ws = (int)(o >> 18);
      long long oo = o & 262143LL;
      src = (ws == 0 ? Wq : (ws == 1 ? Wk : Wv)) + oo;
      dst = w16 + o;
      if (ws == 0) sc = SCALE;
    }
    const float4* p = (const float4*)src;
    float4 f0 = p[0], f1 = p[1];
    half8 v;
    v[0] = (_Float16)(f0.x * sc); v[1] = (_Float16)(f0.y * sc);
    v[2] = (_Float16)(f0.z * sc); v[3] = (_Float16)(f0.w * sc);
    v[4] = (_Float16)(f1.x * sc); v[5] = (_Float16)(f1.y * sc);
    v[6] = (_Float16)(f1.z * sc); v[7] = (_Float16)(f1.w * sc);
    *(half8*)dst = v;
  }
}

// ================= KmmB: Mt[g][e] = fp16(SCALE * sum_fc part[fc][g][e]) =================
__global__ __launch_bounds__(256)
void kmmB(const float* __restrict__ part, _Float16* __restrict__ Mt)
{
  const int idx = blockIdx.x * 256 + threadIdx.x;   // 1024 blocks -> 262144
  float s = 0.f;
  #pragma unroll
  for (int fc = 0; fc < 8; ++fc)
    s += part[(size_t)fc * 262144 + idx];
  Mt[idx] = (_Float16)(s * SCALE);
}

// ================= K1: 128x128 GEMM, fp16 staged, double-buffered, counted vmcnt =================
// ntile 0..3: y = x16 @ Mt^T (row-major out) ; ntile 4..7: vT = (x16 @ Wv^T)^T
__global__ __launch_bounds__(256)
void k1_gemm(const _Float16* __restrict__ x16, const _Float16* __restrict__ w16,
             const _Float16* __restrict__ Mt, _Float16* __restrict__ y16,
             _Float16* __restrict__ vT)
{
  __shared__ _Float16 xs[2][8192];   // 2x16KB, [128 s][64 e], src-swizzled
  __shared__ _Float16 wl[2][8192];   // 2x16KB, [128 n][64 e], src-swizzled

  // bijective XCD swizzle: 2048 blocks = 8 XCDs x 256
  const int id  = blockIdx.x;
  const int swz = (id & 7) * 256 + (id >> 3);
  const int ntile = swz & 7;
  const int stile = swz >> 3;
  const bool vpath = (ntile >= 4);
  const int tid = threadIdx.x, lane = tid & 63, w = tid >> 6;
  const int l15 = lane & 15, h = lane >> 4;
  const int wm = w >> 1, wn = w & 1;

  const _Float16* xb = x16 + (size_t)stile * 128 * 512;
  const _Float16* wb = vpath ? w16 + (size_t)(1024 + (ntile & 3) * 128) * 512
                             : Mt  + (size_t)((ntile & 3) * 128) * 512;

  int rowi[4], coli[4];
  #pragma unroll
  for (int i = 0; i < 4; ++i) {
    int unit = i * 256 + w * 64 + lane;
    int row = unit >> 3, u = unit & 7;
    rowi[i] = row;
    coli[i] = (u ^ (row & 7)) << 3;
  }

  f32x4 acc[4][4] = {};

  #pragma unroll
  for (int i = 0; i < 4; ++i) {
    int ub = i * 256 + w * 64;
    gl16(xb + (size_t)rowi[i] * 512 + coli[i], &xs[0][ub * 8]);
    gl16(wb + (size_t)rowi[i] * 512 + coli[i], &wl[0][ub * 8]);
  }

  for (int kk = 0; kk < 8; ++kk) {
    const int cur = kk & 1;
    if (kk < 7) {
      const int nxt = cur ^ 1;
      #pragma unroll
      for (int i = 0; i < 4; ++i) {
        int ub = i * 256 + w * 64;
        gl16(xb + (size_t)rowi[i] * 512 + (kk + 1) * 64 + coli[i], &xs[nxt][ub * 8]);
        gl16(wb + (size_t)rowi[i] * 512 + (kk + 1) * 64 + coli[i], &wl[nxt][ub * 8]);
      }
      asm volatile("s_waitcnt vmcnt(8)" ::: "memory");
    } else {
      asm volatile("s_waitcnt vmcnt(0)" ::: "memory");
    }
    __builtin_amdgcn_s_barrier();
    __builtin_amdgcn_sched_barrier(0);

    #pragma unroll
    for (int ks = 0; ks < 2; ++ks) {
      half8 a[4], bf[4];
      if (!vpath) {
        #pragma unroll
        for (int mr = 0; mr < 4; ++mr) a[mr]  = ldf64(xs[cur], wm * 64 + mr * 16 + l15, ks * 32 + h * 8);
        #pragma unroll
        for (int nr = 0; nr < 4; ++nr) bf[nr] = ldf64(wl[cur], wn * 64 + nr * 16 + l15, ks * 32 + h * 8);
      } else {
        #pragma unroll
        for (int mr = 0; mr < 4; ++mr) a[mr]  = ldf64(wl[cur], wm * 64 + mr * 16 + l15, ks * 32 + h * 8);
        #pragma unroll
        for (int nr = 0; nr < 4; ++nr) bf[nr] = ldf64(xs[cur], wn * 64 + nr * 16 + l15, ks * 32 + h * 8);
      }
      #pragma unroll
      for (int mr = 0; mr < 4; ++mr)
        #pragma unroll
        for (int nr = 0; nr < 4; ++nr)
          acc[mr][nr] = MFMA(a[mr], bf[nr], acc[mr][nr]);
    }

    __builtin_amdgcn_sched_barrier(0);
    __builtin_amdgcn_s_barrier();
  }

  if (!vpath) {
    const int m0 = stile * 128 + wm * 64;
    const int n0 = (ntile & 3) * 128 + wn * 64;
    #pragma unroll
    for (int mr = 0; mr < 4; ++mr)
      #pragma unroll
      for (int nr = 0; nr < 4; ++nr)
        #pragma unroll
        for (int r = 0; r < 4; ++r)
          y16[(size_t)(m0 + mr * 16 + h * 4 + r) * 512 + n0 + nr * 16 + l15] =
              (_Float16)acc[mr][nr][r];
  } else {
    const int d0 = (ntile & 3) * 128 + wm * 64;
    const int sg = stile * 128 + wn * 64;
    const int bb = sg >> 13, s0 = sg & 8191;
    _Float16* dst = vT + (size_t)bb * 512 * 8192;
    #pragma unroll
    for (int mr = 0; mr < 4; ++mr)
      #pragma unroll
      for (int nr = 0; nr < 4; ++nr)
        #pragma unroll
        for (int r = 0; r < 4; ++r)
          dst[(size_t)(d0 + mr * 16 + h * 4 + r) * 8192 + s0 + nr * 16 + l15] =
              (_Float16)acc[mr][nr][r];
  }
}

// ================= K2: chunked attention; S = y . x16^T ; PV from vT =================
// counted-vmcnt pipeline: stage next -> vmcnt(4) -> barrier -> compute -> barrier.
// PV prologue stage hoisted above softmax (hides L2/L3 latency under VALU).
__global__ __launch_bounds__(256)
void k2_attn(const _Float16* __restrict__ y16, const _Float16* __restrict__ x16,
             const _Float16* __restrict__ vT, float* __restrict__ out)
{
  __shared__ _Float16 kj[2][128 * 64];   // 2x16KB: S: [128 j][64 e] ; PV: [64 d][128 j]
  __shared__ _Float16 p_lds[64 * 128];   // 16KB, [64 q][128 j], swizzled, wave-local use

  const int id = blockIdx.x;             // 512 blocks = 8 XCDs x 64; contiguous c per XCD
  const int sz = (id & 7) * 64 + (id >> 3);
  const int b = sz >> 7, c = sz & 127;
  const int tid = threadIdx.x, lane = tid & 63, w = tid >> 6;
  const int l15 = lane & 15, h = lane >> 4;
  const int jbase = c * 64 - 64;

  const _Float16* qrow = y16 + (size_t)(b * 8192 + c * 64 + w * 16 + l15) * 512;
  half8 qa[16];
  #pragma unroll
  for (int ks = 0; ks < 16; ++ks) qa[ks] = *(const half8*)(qrow + ks * 32 + h * 8);

  const _Float16* kb = x16 + (size_t)b * 8192 * 512;
  const _Float16* vb = vT + (size_t)b * 512 * 8192;

  int srow[4], scol[4];
  #pragma unroll
  for (int i = 0; i < 4; ++i) {
    int unit = i * 256 + w * 64 + lane;
    int row = unit >> 3, u = unit & 7;
    int sj = jbase + row; if (sj < 0) sj = 0;   // c==0: masked below
    srow[i] = sj;
    scol[i] = (u ^ (row & 7)) << 3;
  }
  int prow[4], pjs[4];
  #pragma unroll
  for (int i = 0; i < 4; ++i) {
    int unit = i * 256 + w * 64 + lane;
    int row = unit >> 4, u = unit & 15;
    int u2 = (u & 8) | ((u & 7) ^ (row & 7));
    int js = jbase + u2 * 8; if (js < 0) js = 0; // c==0: p==0 exactly there
    prow[i] = row;
    pjs[i] = js;
  }

  // ---- S phase: counted-vmcnt pipeline ----
  f32x4 S[8] = {};
  #pragma unroll
  for (int i = 0; i < 4; ++i)
    gl16(kb + (size_t)srow[i] * 512 + scol[i], &kj[0][(i * 256 + w * 64) * 8]);

  #pragma unroll
  for (int ee = 0; ee < 8; ++ee) {
    if (ee < 7) {
      #pragma unroll
      for (int i = 0; i < 4; ++i)
        gl16(kb + (size_t)srow[i] * 512 + (ee + 1) * 64 + scol[i],
             &kj[(ee + 1) & 1][(i * 256 + w * 64) * 8]);
      asm volatile("s_waitcnt vmcnt(4)" ::: "memory");
    } else {
      asm volatile("s_waitcnt vmcnt(0)" ::: "memory");
    }
    __builtin_amdgcn_s_barrier();
    __builtin_amdgcn_sched_barrier(0);

    #pragma unroll
    for (int ks = 0; ks < 2; ++ks) {
      #pragma unroll
      for (int nt = 0; nt < 8; ++nt) {
        half8 bf = ldf64(kj[ee & 1], nt * 16 + l15, ks * 32 + h * 8);
        S[nt] = MFMA(qa[ee * 2 + ks], bf, S[nt]);
      }
    }
    __builtin_amdgcn_sched_barrier(0);
    __builtin_amdgcn_s_barrier();
  }

  // ---- PV prologue stage (hoisted above softmax) ----
  #pragma unroll
  for (int i = 0; i < 4; ++i)
    gl16(vb + (size_t)prow[i] * 8192 + pjs[i], &kj[0][(i * 256 + w * 64) * 8]);

  // ---- masked softmax (VALU; overlaps PV prologue loads) ----
  #pragma unroll
  for (int jt = 0; jt < 8; ++jt) {
    int j = jt * 16 + l15;
    #pragma unroll
    for (int r = 0; r < 4; ++r) {
      int ql = w * 16 + h * 4 + r;
      bool valid = (j < 64 + ql) && ((c > 0) || (j >= 64));
      S[jt][r] = valid ? S[jt][r] : -1e30f;
    }
  }
  #pragma unroll
  for (int r = 0; r < 4; ++r) {
    float mx = -1e30f;
    #pragma unroll
    for (int jt = 0; jt < 8; ++jt) mx = fmaxf(mx, S[jt][r]);
    mx = fmaxf(mx, __shfl_xor(mx, 1));
    mx = fmaxf(mx, __shfl_xor(mx, 2));
    mx = fmaxf(mx, __shfl_xor(mx, 4));
    mx = fmaxf(mx, __shfl_xor(mx, 8));
    float sum = 0.f;
    #pragma unroll
    for (int jt = 0; jt < 8; ++jt) {
      float sv = S[jt][r];
      float pe = (sv > -1e29f) ? __expf(sv - mx) : 0.f;
      S[jt][r] = pe;
      sum += pe;
    }
    sum += __shfl_xor(sum, 1);
    sum += __shfl_xor(sum, 2);
    sum += __shfl_xor(sum, 4);
    sum += __shfl_xor(sum, 8);
    float inv = (sum > 0.f) ? (1.0f / sum) : 0.f;   // fully-masked row -> p = 0
    #pragma unroll
    for (int jt = 0; jt < 8; ++jt) {
      int row = w * 16 + h * 4 + r, col = jt * 16 + l15;
      _Float16 ph = (_Float16)(S[jt][r] * inv);
      *(_Float16*)((char*)p_lds + row * 256 + ((col << 1) ^ ((row & 7) << 4))) = ph;
    }
  }
  half8 pa[4];
  #pragma unroll
  for (int ks = 0; ks < 4; ++ks) {
    int row = w * 16 + l15, colh = ks * 32 + h * 8;
    pa[ks] = *(const half8*)((const char*)p_lds + row * 256 + ((colh << 1) ^ ((row & 7) << 4)));
  }

  // ---- PV phase: counted-vmcnt pipeline ----
  float* ob = out + (size_t)(b * 8192 + c * 64 + w * 16) * 512;
  #pragma unroll
  for (int dd = 0; dd < 8; ++dd) {
    if (dd < 7) {
      #pragma unroll
      for (int i = 0; i < 4; ++i)
        gl16(vb + (size_t)((dd + 1) * 64 + prow[i]) * 8192 + pjs[i],
             &kj[(dd + 1) & 1][(i * 256 + w * 64) * 8]);
      asm volatile("s_waitcnt vmcnt(4)" ::: "memory");   // over-waits retired stores: safe
    } else {
      asm volatile("s_waitcnt vmcnt(0)" ::: "memory");
    }
    __builtin_amdgcn_s_barrier();
    __builtin_amdgcn_sched_barrier(0);

    f32x4 o[4] = {};
    #pragma unroll
    for (int ks = 0; ks < 4; ++ks) {
      #pragma unroll
      for (int nr = 0; nr < 4; ++nr) {
        half8 bf = ldf128(kj[dd & 1], nr * 16 + l15, ks * 32 + h * 8);
        o[nr] = MFMA(pa[ks], bf, o[nr]);
      }
    }
    #pragma unroll
    for (int nr = 0; nr < 4; ++nr)
      #pragma unroll
      for (int r = 0; r < 4; ++r)
        ob[(size_t)(h * 4 + r) * 512 + dd * 64 + nr * 16 + l15] = o[nr][r];
    __builtin_amdgcn_sched_barrier(0);
    __builtin_amdgcn_s_barrier();
  }
}

// ================= fallback: round-1 fused kernel (used only if ws too small) =================
__device__ __forceinline__ int swzb(int row, int colByte) {
  return colByte ^ ((row & 7) << 4);
}
__device__ __forceinline__ half8 ldw_frag(const float* __restrict__ W, int row, int e0) {
  const float4* p = reinterpret_cast<const float4*>(W + ((size_t)row << 9) + e0);
  float4 f0 = p[0];
  float4 f1 = p[1];
  half8 v;
  v[0] = (_Float16)f0.x; v[1] = (_Float16)f0.y; v[2] = (_Float16)f0.z; v[3] = (_Float16)f0.w;
  v[4] = (_Float16)f1.x; v[5] = (_Float16)f1.y; v[6] = (_Float16)f1.z; v[7] = (_Float16)f1.w;
  return v;
}
__device__ __forceinline__ half8 ldl_frag(const unsigned short* buf, int row, int col, int strideBytes) {
  int byte = row * strideBytes + swzb(row, col << 1);
  return *reinterpret_cast<const half8*>(reinterpret_cast<const char*>(buf) + byte);
}

__global__ __launch_bounds__(256, 1)
void ep_fused(const float* __restrict__ x, const float* __restrict__ Wq,
              const float* __restrict__ Wk, const float* __restrict__ Wv,
              float* __restrict__ out)
{
  __shared__ unsigned short xs[128 * 512];
  __shared__ unsigned short kv[64 * 128];
  __shared__ unsigned short pq[64 * 128];

  const int bc   = blockIdx.x;
  const int b    = bc >> 7;
  const int c    = bc & 127;
  const int tid  = threadIdx.x;
  const int lane = tid & 63;
  const int w    = tid >> 6;
  const int l15  = lane & 15;
  const int h    = lane >> 4;

  const float* xb = x + (size_t)b * (8192 * 512);
  #pragma unroll
  for (int i = 0; i < 32; ++i) {
    int unit = tid + (i << 8);
    int row  = unit >> 6;
    int e0   = (unit & 63) << 3;
    half8 v;
    if (c == 0 && row < 64) {
      #pragma unroll
      for (int t = 0; t < 8; ++t) v[t] = (_Float16)0.0f;
    } else {
      int s = c * 64 - 64 + row;
      const float4* p = reinterpret_cast<const float4*>(xb + (size_t)s * 512 + e0);
      float4 f0 = p[0], f1 = p[1];
      v[0] = (_Float16)f0.x; v[1] = (_Float16)f0.y; v[2] = (_Float16)f0.z; v[3] = (_Float16)f0.w;
      v[4] = (_Float16)f1.x; v[5] = (_Float16)f1.y; v[6] = (_Float16)f1.z; v[7] = (_Float16)f1.w;
    }
    int byte = (row << 10) + swzb(row, e0 << 1);
    *reinterpret_cast<half8*>(reinterpret_cast<char*>(xs) + byte) = v;
  }
  __syncthreads();

  f32x4 Sacc[8] = {};
  const int d0 = (w << 4) + (h << 2);

  for (int dt = 0; dt < 8; ++dt) {
    const int drow = (dt << 6) + (w << 4) + l15;

    f32x4 qa[4] = {};
    for (int ks = 0; ks < 16; ++ks) {
      half8 a = ldw_frag(Wq, drow, (ks << 5) + (h << 3));
      #pragma unroll
      for (int nt = 0; nt < 4; ++nt) {
        half8 bf = ldl_frag(xs, 64 + (nt << 4) + l15, (ks << 5) + (h << 3), 1024);
        qa[nt] = MFMA(a, bf, qa[nt]);
      }
    }
    #pragma unroll
    for (int nt = 0; nt < 4; ++nt) {
      int q = (nt << 4) + l15;
      half4 hv;
      hv[0] = (_Float16)qa[nt][0]; hv[1] = (_Float16)qa[nt][1];
      hv[2] = (_Float16)qa[nt][2]; hv[3] = (_Float16)qa[nt][3];
      *reinterpret_cast<half4*>(reinterpret_cast<char*>(pq) + q * 128 + swzb(q, d0 << 1)) = hv;
    }

    f32x4 ka[8] = {};
    for (int ks = 0; ks < 16; ++ks) {
      half8 a = ldw_frag(Wk, drow, (ks << 5) + (h << 3));
      #pragma unroll
      for (int nt = 0; nt < 8; ++nt) {
        half8 bf = ldl_frag(xs, (nt << 4) + l15, (ks << 5) + (h << 3), 1024);
        ka[nt] = MFMA(a, bf, ka[nt]);
      }
    }
    #pragma unroll
    for (int nt = 0; nt < 8; ++nt) {
      int j = (nt << 4) + l15;
      half4 hv;
      hv[0] = (_Float16)ka[nt][0]; hv[1] = (_Float16)ka[nt][1];
      hv[2] = (_Float16)ka[nt][2]; hv[3] = (_Float16)ka[nt][3];
      *reinterpret_cast<half4*>(reinterpret_cast<char*>(kv) + j * 128 + swzb(j, d0 << 1)) = hv;
    }
    __syncthreads();

    #pragma unroll
    for (int ksd = 0; ksd < 2; ++ksd) {
      half8 a = ldl_frag(pq, (w << 4) + l15, (ksd << 5) + (h << 3), 128);
      #pragma unroll
      for (int nt = 0; nt < 8; ++nt) {
        half8 bf = ldl_frag(kv, (nt << 4) + l15, (ksd << 5) + (h << 3), 128);
        Sacc[nt] = MFMA(a, bf, Sacc[nt]);
      }
    }
    __syncthreads();
  }

  const float scale = SCALE;
  #pragma unroll
  for (int nt = 0; nt < 8; ++nt) {
    int j = (nt << 4) + l15;
    #pragma unroll
    for (int r = 0; r < 4; ++r) {
      int qrow = (w << 4) + (h << 2) + r;
      bool valid = (j < 64 + qrow) && ((c > 0) || (j >= 64));
      Sacc[nt][r] = valid ? Sacc[nt][r] * scale : -1e30f;
    }
  }
  float inv[4];
  #pragma unroll
  for (int r = 0; r < 4; ++r) {
    float mx = -1e30f;
    #pragma unroll
    for (int nt = 0; nt < 8; ++nt) mx = fmaxf(mx, Sacc[nt][r]);
    mx = fmaxf(mx, __shfl_xor(mx, 1));
    mx = fmaxf(mx, __shfl_xor(mx, 2));
    mx = fmaxf(mx, __shfl_xor(mx, 4));
    mx = fmaxf(mx, __shfl_xor(mx, 8));
    float sum = 0.f;
    #pragma unroll
    for (int nt = 0; nt < 8; ++nt) {
      float sv = Sacc[nt][r];
      float pe = (sv > -1e29f) ? __expf(sv - mx) : 0.f;
      Sacc[nt][r] = pe;
      sum += pe;
    }
    sum += __shfl_xor(sum, 1);
    sum += __shfl_xor(sum, 2);
    sum += __shfl_xor(sum, 4);
    sum += __shfl_xor(sum, 8);
    inv[r] = (sum > 0.f) ? (1.0f / sum) : 0.f;
  }
  #pragma unroll
  for (int nt = 0; nt < 8; ++nt) {
    int j = (nt << 4) + l15;
    #pragma unroll
    for (int r = 0; r < 4; ++r) {
      int qrow = (w << 4) + (h << 2) + r;
      _Float16 ph = (_Float16)(Sacc[nt][r] * inv[r]);
      *reinterpret_cast<_Float16*>(reinterpret_cast<char*>(pq) + qrow * 256 + swzb(qrow, j << 1)) = ph;
    }
  }
  __syncthreads();

  for (int dt = 0; dt < 8; ++dt) {
    const int dcol = (dt << 6) + (w << 4) + l15;

    f32x4 va[8] = {};
    for (int ks = 0; ks < 16; ++ks) {
      half8 bf = ldw_frag(Wv, dcol, (ks << 5) + (h << 3));
      #pragma unroll
      for (int mt = 0; mt < 8; ++mt) {
        half8 a = ldl_frag(xs, (mt << 4) + l15, (ks << 5) + (h << 3), 1024);
        va[mt] = MFMA(a, bf, va[mt]);
      }
    }
    {
      int dl = (w << 4) + l15;
      #pragma unroll
      for (int mt = 0; mt < 8; ++mt) {
        int j0 = (mt << 4) + (h << 2);
        half4 hv;
        hv[0] = (_Float16)va[mt][0]; hv[1] = (_Float16)va[mt][1];
        hv[2] = (_Float16)va[mt][2]; hv[3] = (_Float16)va[mt][3];
        *reinterpret_cast<half4*>(reinterpret_cast<char*>(kv) + dl * 256 + swzb(dl, j0 << 1)) = hv;
      }
    }
    __syncthreads();

    f32x4 oa[4] = {};
    #pragma unroll
    for (int ks = 0; ks < 4; ++ks) {
      half8 a = ldl_frag(pq, (w << 4) + l15, (ks << 5) + (h << 3), 256);
      #pragma unroll
      for (int nt = 0; nt < 4; ++nt) {
        half8 bf = ldl_frag(kv, (nt << 4) + l15, (ks << 5) + (h << 3), 256);
        oa[nt] = MFMA(a, bf, oa[nt]);
      }
    }
    #pragma unroll
    for (int nt = 0; nt < 4; ++nt) {
      int d = (dt << 6) + (nt << 4) + l15;
      #pragma unroll
      for (int r = 0; r < 4; ++r) {
        int qrow = (w << 4) + (h << 2) + r;
        out[((size_t)(b * 8192 + (c << 6) + qrow) << 9) + d] = oa[nt][r];
      }
    }
    __syncthreads();
  }
}

extern "C" void kernel_launch(void* const* d_in, const int* in_sizes, int n_in,
                              void* d_out, int out_size, void* d_ws, size_t ws_size,
                              hipStream_t stream) {
  const float* x  = (const float*)d_in[0];
  const float* Wq = (const float*)d_in[1];
  const float* Wk = (const float*)d_in[2];
  const float* Wv = (const float*)d_in[3];
  float* out = (float*)d_out;
  (void)in_sizes; (void)n_in; (void)out_size;

  if (d_ws != nullptr && ws_size >= WS_NEED) {
    char* ws = (char*)d_ws;
    _Float16* x16 = (_Float16*)(ws + X16_OFF);
    _Float16* y16 = (_Float16*)(ws + Y16_OFF);
    _Float16* Mt  = (_Float16*)(ws + MT_OFF);
    float*    Mp  = (float*)(ws + MP_OFF);
    _Float16* vT  = (_Float16*)(ws + VT_OFF);
    _Float16* w16 = (_Float16*)(ws + W16_OFF);

    hipLaunchKernelGGL(k0m, dim3(9088), dim3(256), 0, stream, x, Wq, Wk, Wv, x16, w16, Mp);
    hipLaunchKernelGGL(kmmB, dim3(1024), dim3(256), 0, stream, Mp, Mt);
    hipLaunchKernelGGL(k1_gemm, dim3(2048), dim3(256), 0, stream, x16, w16, Mt, y16, vT);
    hipLaunchKernelGGL(k2_attn, dim3(512), dim3(256), 0, stream, y16, x16, vT, out);
  } else {
    hipLaunchKernelGGL(ep_fused, dim3(512), dim3(256), 0, stream, x, Wq, Wk, Wv, out);
  }
}